// Round 1
// baseline (716.216 us; speedup 1.0000x reference)
//
#include <hip/hip_runtime.h>
#include <math.h>

#define SDIM 1024
#define DDIM 512
#define NRBF 8
#define FEAT 20

static __device__ __forceinline__ float wave_red_sum(float v) {
#pragma unroll
  for (int off = 32; off > 0; off >>= 1) v += __shfl_xor(v, off, 64);
  return v;
}
static __device__ __forceinline__ float wave_red_max(float v) {
#pragma unroll
  for (int off = 32; off > 0; off >>= 1) v = fmaxf(v, __shfl_xor(v, off, 64));
  return v;
}
static __device__ __forceinline__ float wave_red_min(float v) {
#pragma unroll
  for (int off = 32; off > 0; off >>= 1) v = fminf(v, __shfl_xor(v, off, 64));
  return v;
}

__global__ void __launch_bounds__(256) corr_node_kernel(
    const float* __restrict__ x, const float* __restrict__ Cmat,
    const unsigned char* __restrict__ mask,
    const float* __restrict__ W, const float* __restrict__ bias,
    const float* __restrict__ gamma, const float* __restrict__ beta,
    const float* __restrict__ gatep,
    const float* __restrict__ centers, const float* __restrict__ widths,
    float* __restrict__ out, int nrows)
{
  __shared__ float Wl[FEAT * DDIM];  // 40 KB -> 4 blocks/CU

  const int tid = threadIdx.x;
  // Stage W (20x512 f32) into LDS, contiguous float4 copy (10 iters/thread).
  {
    const float4* Wg = (const float4*)W;
    float4* Wd = (float4*)Wl;
#pragma unroll
    for (int i = 0; i < (FEAT * DDIM / 4) / 256; ++i)
      Wd[i * 256 + tid] = Wg[i * 256 + tid];
  }

  const float gate = gatep[0];
  float cen[NRBF], iwid[NRBF];
#pragma unroll
  for (int j = 0; j < NRBF; ++j) {
    cen[j] = centers[j];
    iwid[j] = 1.0f / (widths[j] + 1e-6f);
  }

  const int lane = tid & 63;
  const int wv = tid >> 6;
  const int gw = blockIdx.x * 4 + wv;
  const int nw = gridDim.x * 4;

  // Per-lane persistent params for this lane's 8 dims: {4*lane..+3, 256+4*lane..+3}
  const float4* g4 = (const float4*)gamma;
  const float4* b4 = (const float4*)beta;
  const float4* pb4 = (const float4*)bias;
  const float4 ga0 = g4[lane], ga1 = g4[64 + lane];
  const float4 be0 = b4[lane], be1 = b4[64 + lane];
  const float4 pb0 = pb4[lane], pb1 = pb4[64 + lane];

  __syncthreads();  // W staged; no further barriers

  const float4* Wl4 = (const float4*)Wl;

  for (int row = gw; row < nrows; row += nw) {
    // ---- C row: 1024 f32, 16 per lane as 4x float4 (coalesced 1KB/instr) ----
    const float4* crow = (const float4*)(Cmat + (size_t)row * SDIM);
    float4 cv[4];
#pragma unroll
    for (int j = 0; j < 4; ++j) cv[j] = crow[j * 64 + lane];

    float s = 0.f, mx = -1e30f, mn = 1e30f;
#pragma unroll
    for (int j = 0; j < 4; ++j) {
      float* p = (float*)(&cv[j]);
#pragma unroll
      for (int q = 0; q < 4; ++q) {
        float c = fminf(fmaxf(p[q], 0.f), 1.f);
        p[q] = c;
        s += c;
        mx = fmaxf(mx, c);
        mn = fminf(mn, c);
      }
    }
    s = wave_red_sum(s);
    mx = wave_red_max(mx);
    mn = wave_red_min(mn);
    const float mean = s * (1.0f / SDIM);

    float ss = 0.f;
#pragma unroll
    for (int j = 0; j < 4; ++j) {
      const float* p = (const float*)(&cv[j]);
#pragma unroll
      for (int q = 0; q < 4; ++q) {
        float dv = p[q] - mean;
        ss += dv * dv;
      }
    }
    ss = wave_red_sum(ss);
    const float sd = sqrtf(ss * (1.0f / SDIM));

    // ---- 20-dim feature vector (all lanes redundantly; trivial VALU) ----
    float z[FEAT];
    z[0] = mean; z[1] = mx; z[2] = mn; z[3] = sd;
#pragma unroll
    for (int j = 0; j < NRBF; ++j) {
      const float dm = (mean - cen[j]) * iwid[j];
      const float dx = (mx - cen[j]) * iwid[j];
      z[4 + j]  = __expf(-0.5f * dm * dm);
      z[12 + j] = __expf(-0.5f * dx * dx);
    }

    // ---- pe = z @ W + b for this lane's 8 dims (LDS ds_read_b128 stream) ----
    float4 pe0 = pb0, pe1 = pb1;
#pragma unroll
    for (int k = 0; k < FEAT; ++k) {
      const float zk = z[k];
      const float4 w0 = Wl4[k * 128 + lane];
      const float4 w1 = Wl4[k * 128 + 64 + lane];
      pe0.x += zk * w0.x; pe0.y += zk * w0.y; pe0.z += zk * w0.z; pe0.w += zk * w0.w;
      pe1.x += zk * w1.x; pe1.y += zk * w1.y; pe1.z += zk * w1.z; pe1.w += zk * w1.w;
    }

    // ---- LayerNorm over 512 (two-pass, shuffle reductions) ----
    float psum = pe0.x + pe0.y + pe0.z + pe0.w + pe1.x + pe1.y + pe1.z + pe1.w;
    psum = wave_red_sum(psum);
    const float mu = psum * (1.0f / DDIM);

    float d0 = pe0.x - mu, d1 = pe0.y - mu, d2 = pe0.z - mu, d3 = pe0.w - mu;
    float d4 = pe1.x - mu, d5 = pe1.y - mu, d6 = pe1.z - mu, d7 = pe1.w - mu;
    float vs = d0 * d0 + d1 * d1 + d2 * d2 + d3 * d3 +
               d4 * d4 + d5 * d5 + d6 * d6 + d7 * d7;
    vs = wave_red_sum(vs);
    const float rstd = rsqrtf(vs * (1.0f / DDIM) + 1e-5f);

    const float keep = mask[row] ? 0.0f : gate;  // masked -> pe contributes 0

    // ---- epilogue: out = x + keep * (norm(pe)*gamma + beta), coalesced f4 ----
    const float4* xr = (const float4*)(x + (size_t)row * DDIM);
    float4* orow = (float4*)(out + (size_t)row * DDIM);
    const float4 x0 = xr[lane], x1 = xr[64 + lane];
    float4 o0, o1;
    o0.x = x0.x + keep * (d0 * rstd * ga0.x + be0.x);
    o0.y = x0.y + keep * (d1 * rstd * ga0.y + be0.y);
    o0.z = x0.z + keep * (d2 * rstd * ga0.z + be0.z);
    o0.w = x0.w + keep * (d3 * rstd * ga0.w + be0.w);
    o1.x = x1.x + keep * (d4 * rstd * ga1.x + be1.x);
    o1.y = x1.y + keep * (d5 * rstd * ga1.y + be1.y);
    o1.z = x1.z + keep * (d6 * rstd * ga1.z + be1.z);
    o1.w = x1.w + keep * (d7 * rstd * ga1.w + be1.w);
    orow[lane] = o0;
    orow[64 + lane] = o1;
  }
}

extern "C" void kernel_launch(void* const* d_in, const int* in_sizes, int n_in,
                              void* d_out, int out_size, void* d_ws, size_t ws_size,
                              hipStream_t stream) {
  const float* x = (const float*)d_in[0];
  const float* Cmat = (const float*)d_in[1];
  const unsigned char* mask = (const unsigned char*)d_in[2];
  const float* W = (const float*)d_in[3];
  const float* bias = (const float*)d_in[4];
  const float* gamma = (const float*)d_in[5];
  const float* beta = (const float*)d_in[6];
  const float* gate = (const float*)d_in[7];
  const float* centers = (const float*)d_in[8];
  const float* widths = (const float*)d_in[9];
  float* out = (float*)d_out;

  const int nrows = in_sizes[0] / DDIM;  // 100000

  // 1024 blocks x 256 threads: 4 blocks/CU (40KB LDS each), fully resident,
  // grid-stride over rows with one wave per row.
  corr_node_kernel<<<1024, 256, 0, stream>>>(
      x, Cmat, mask, W, bias, gamma, beta, gate, centers, widths, out, nrows);
}